// Round 2
// baseline (48.668 us; speedup 1.0000x reference)
//
#include <hip/hip_runtime.h>

// LSTM_8589935226: B=4194304 independent LSTMs, T=4, I=1, H=2, C=1.
// Round 2: transcendental-count reduction.
//   - Activations via [7/6] Pade rationals (no v_exp at all).
//   - Montgomery batched inversion: 2 v_rcp per timestep total (was 20 trans).
//   - float2 (ext_vector) math so hipcc emits v_pk_*_f32 packed ops.
//   - t=0 specialized (h=c=0 -> forget gate dead, gates affine in x0).

typedef float v2 __attribute__((ext_vector_type(2)));

__device__ __forceinline__ float frcp(float x) { return __builtin_amdgcn_rcpf(x); }
__device__ __forceinline__ v2 mk2(float a, float b) { v2 r; r[0] = a; r[1] = b; return r; }
__device__ __forceinline__ v2 sp2(float a) { v2 r; r[0] = a; r[1] = a; return r; }
__device__ __forceinline__ v2 vfma2(v2 a, v2 b, v2 c) { return __builtin_elementwise_fma(a, b, c); }
__device__ __forceinline__ v2 vclamp2(v2 x, float lim) {
    return __builtin_elementwise_min(__builtin_elementwise_max(x, sp2(-lim)), sp2(lim));
}

// tanh(x) ~= x*N(x^2)/D(x^2), [7/6] Pade (coeffs normalized by 135135).
// With clamp |x|<=4: abs err <= ~6.6e-4 (beyond clamp), <=2e-5 inside.
#define TA1 0.12820513f
#define TA2 0.0027972028f
#define TA3 7.4000814e-06f
#define TB1 0.46153846f
#define TB2 0.023310023f
#define TB3 2.0720021e-04f
// sigmoid(u) = 0.5 + u*Ns(u^2)/Ds(u^2) (tanh(u/2) folded). Clamp |u|<=8,
// abs err <= ~3.3e-4.
#define SC0 0.25f
#define SC1 0.0080128205f
#define SC2 4.3706294e-05f
#define SC3 2.8906566e-08f
#define SD1 0.11538462f
#define SD2 0.0014568765f
#define SD3 3.2375033e-06f

struct ND { v2 n, d; };  // numerator, (positive) denominator

__device__ __forceinline__ ND tanh_nd(v2 x) {
    x = vclamp2(x, 4.0f);
    v2 t = x * x;
    v2 q = vfma2(t, sp2(TA3), sp2(TA2));
    q = vfma2(q, t, sp2(TA1));
    q = vfma2(q, t, sp2(1.0f));
    v2 r = vfma2(t, sp2(TB3), sp2(TB2));
    r = vfma2(r, t, sp2(TB1));
    r = vfma2(r, t, sp2(1.0f));
    ND o; o.n = x * q; o.d = r; return o;
}

__device__ __forceinline__ ND sig_nd(v2 u) {
    u = vclamp2(u, 8.0f);
    v2 t = u * u;
    v2 q = vfma2(t, sp2(SC3), sp2(SC2));
    q = vfma2(q, t, sp2(SC1));
    q = vfma2(q, t, sp2(SC0));
    v2 r = vfma2(t, sp2(SD3), sp2(SD2));
    r = vfma2(r, t, sp2(SD1));
    r = vfma2(r, t, sp2(1.0f));
    ND o; o.n = u * q; o.d = r; return o;
}

// tanh of a pair with its own paired reciprocal (1 rcp).
__device__ __forceinline__ v2 tanh_pair(v2 x) {
    ND a = tanh_nd(x);
    float r = frcp(a.d[0] * a.d[1]);
    return a.n * mk2(r * a.d[1], r * a.d[0]);
}

__global__ __launch_bounds__(256) void lstm_fused(
    const float4* __restrict__ x,     // [B] float4 = 4 timesteps (I=1)
    const float*  __restrict__ W_ih,  // [8]
    const float*  __restrict__ W_hh,  // [16] row-major (8x2)
    const float*  __restrict__ b_ih,  // [8]
    const float*  __restrict__ b_hh,  // [8]
    const float*  __restrict__ W_fc,  // [2]
    const float*  __restrict__ b_fc,  // [1]
    float* __restrict__ out,          // [B]
    int B)
{
    int idx = blockIdx.x * blockDim.x + threadIdx.x;
    if (idx >= B) return;

    // Grid-uniform weights -> scalar loads. Pack per gate-pair:
    // gate order i(0,1) f(2,3) g(4,5) o(6,7).
    v2 WI[4], WH0[4], WH1[4], BB[4];
#pragma unroll
    for (int p = 0; p < 4; ++p) {
        WI[p]  = mk2(W_ih[2 * p], W_ih[2 * p + 1]);
        WH0[p] = mk2(W_hh[4 * p], W_hh[4 * p + 2]);      // W_hh[2g+0], g=2p,2p+1
        WH1[p] = mk2(W_hh[4 * p + 1], W_hh[4 * p + 3]);  // W_hh[2g+1]
        BB[p]  = mk2(b_ih[2 * p] + b_hh[2 * p], b_ih[2 * p + 1] + b_hh[2 * p + 1]);
    }
    const float wf0 = W_fc[0], wf1 = W_fc[1], bf = b_fc[0];
    const v2 HALF = sp2(0.5f);

    const float4 xv = x[idx];
    const float xs[3] = {xv.y, xv.z, xv.w};

    // ---- t = 0: h = c = 0. Forget gate is dead (c=0). Gates affine in x0.
    v2 h, c;
    {
        const v2 x0 = sp2(xv.x);
        ND ni = sig_nd (vfma2(x0, WI[0], BB[0]));
        ND ng = tanh_nd(vfma2(x0, WI[2], BB[2]));
        ND no = sig_nd (vfma2(x0, WI[3], BB[3]));
        // Montgomery over 6 positive denominators: 1 rcp total.
        const float d0 = ni.d[0], d1 = ni.d[1], d2 = ng.d[0],
                    d3 = ng.d[1], d4 = no.d[0], d5 = no.d[1];
        const float p1 = d0 * d1, p2 = p1 * d2, p3 = p2 * d3, p4 = p3 * d4,
                    p5 = p4 * d5;
        float R = frcp(p5);
        const float i5 = R * p4; R *= d5;
        const float i4 = R * p3; R *= d4;
        const float i3 = R * p2; R *= d3;
        const float i2 = R * p1; R *= d2;
        const float i1 = R * d0; R *= d1;
        const float i0 = R;
        const v2 I  = vfma2(ni.n, mk2(i0, i1), HALF);
        const v2 Gt = ng.n * mk2(i2, i3);
        const v2 O  = vfma2(no.n, mk2(i4, i5), HALF);
        c = I * Gt;
        h = O * tanh_pair(c);
    }

    // ---- t = 1..3
#pragma unroll
    for (int t = 0; t < 3; ++t) {
        const v2 xt = sp2(xs[t]);
        const v2 h0 = sp2(h[0]), h1 = sp2(h[1]);
        ND ni = sig_nd (vfma2(xt, WI[0], vfma2(h0, WH0[0], vfma2(h1, WH1[0], BB[0]))));
        ND nf = sig_nd (vfma2(xt, WI[1], vfma2(h0, WH0[1], vfma2(h1, WH1[1], BB[1]))));
        ND ng = tanh_nd(vfma2(xt, WI[2], vfma2(h0, WH0[2], vfma2(h1, WH1[2], BB[2]))));
        ND no = sig_nd (vfma2(xt, WI[3], vfma2(h0, WH0[3], vfma2(h1, WH1[3], BB[3]))));
        // Montgomery over 8 positive denominators (each in [1,15.2]): 1 rcp.
        const float d0 = ni.d[0], d1 = ni.d[1], d2 = nf.d[0], d3 = nf.d[1],
                    d4 = ng.d[0], d5 = ng.d[1], d6 = no.d[0], d7 = no.d[1];
        const float p1 = d0 * d1, p2 = p1 * d2, p3 = p2 * d3, p4 = p3 * d4,
                    p5 = p4 * d5, p6 = p5 * d6, p7 = p6 * d7;
        float R = frcp(p7);
        const float i7 = R * p6; R *= d7;
        const float i6 = R * p5; R *= d6;
        const float i5 = R * p4; R *= d5;
        const float i4 = R * p3; R *= d4;
        const float i3 = R * p2; R *= d3;
        const float i2 = R * p1; R *= d2;
        const float i1 = R * d0; R *= d1;
        const float i0 = R;
        const v2 I  = vfma2(ni.n, mk2(i0, i1), HALF);
        const v2 F  = vfma2(nf.n, mk2(i2, i3), HALF);
        const v2 Gt = ng.n * mk2(i4, i5);
        const v2 O  = vfma2(no.n, mk2(i6, i7), HALF);
        c = vfma2(F, c, I * Gt);
        h = O * tanh_pair(c);
    }

    out[idx] = fmaf(h[0], wf0, fmaf(h[1], wf1, bf));
}

extern "C" void kernel_launch(void* const* d_in, const int* in_sizes, int n_in,
                              void* d_out, int out_size, void* d_ws, size_t ws_size,
                              hipStream_t stream)
{
    const float4* x    = (const float4*)d_in[0];
    const float*  W_ih = (const float*)d_in[1];
    const float*  W_hh = (const float*)d_in[2];
    const float*  b_ih = (const float*)d_in[3];
    const float*  b_hh = (const float*)d_in[4];
    const float*  W_fc = (const float*)d_in[5];
    const float*  b_fc = (const float*)d_in[6];
    float* out = (float*)d_out;

    const int B = in_sizes[0] / 4;
    const int threads = 256;
    const int blocks = (B + threads - 1) / threads;
    lstm_fused<<<blocks, threads, 0, stream>>>(x, W_ih, W_hh, b_ih, b_hh,
                                               W_fc, b_fc, out, B);
}

// Round 3
// 46.015 us; speedup vs baseline: 1.0577x; 1.0577x over previous
//
#include <hip/hip_runtime.h>

// LSTM_8589935226: B=4194304 independent LSTMs, T=4, I=1, H=2, C=1.
// Round 3: exp2-based activations (cheap, tight scalar codegen) + Montgomery
// batched reciprocals (2 rcp/timestep) + log2e scales folded into weights
// + scaled cell-state domain (c' = 2*log2e*c) so tanh(c) = (2^c'-1)/(2^c'+1).
// Issue-cost model: cyc = 2*V + 16*T. Round1: V=230,T=80 -> 1740 (meas 1747).
// This kernel: V~300, T~38 -> ~1340 cyc -> predict ~35 us.

__device__ __forceinline__ float fexp2(float x) { return __builtin_amdgcn_exp2f(x); }
__device__ __forceinline__ float frcp(float x)  { return __builtin_amdgcn_rcpf(x); }

__global__ __launch_bounds__(256) void lstm_fused(
    const float4* __restrict__ x,     // [B] float4 = 4 timesteps (I=1)
    const float*  __restrict__ W_ih,  // [8]
    const float*  __restrict__ W_hh,  // [16] row-major (8x2)
    const float*  __restrict__ b_ih,  // [8]
    const float*  __restrict__ b_hh,  // [8]
    const float*  __restrict__ W_fc,  // [2]
    const float*  __restrict__ b_fc,  // [1]
    float* __restrict__ out,          // [B]
    int B)
{
    const int idx = blockIdx.x * blockDim.x + threadIdx.x;
    if (idx >= B) return;

    const float L2E = 1.4426950408889634f;   // log2(e)
    const float S2  = 2.8853900817779268f;   // 2*log2(e)

    // Gate rows: i(0,1) f(2,3) g(4,5) o(6,7).
    // Sigmoid rows pre-scaled by -log2e: e = 2^pre = exp(-raw) -> sig = 1/(1+e).
    // g rows pre-scaled by +2*log2e:     e = 2^pre = exp(2*raw) -> tanh = (e-1)/(e+1).
    const float sc[8] = {-L2E, -L2E, -L2E, -L2E, S2, S2, -L2E, -L2E};

    float wi[8], wh0[8], wh1[8], bb[8];
#pragma unroll
    for (int k = 0; k < 8; ++k) {
        const float s = sc[k];
        wi[k]  = W_ih[k] * s;
        wh0[k] = W_hh[2 * k] * s;
        wh1[k] = W_hh[2 * k + 1] * s;
        bb[k]  = (b_ih[k] + b_hh[k]) * s;
    }
    const float wf0 = W_fc[0], wf1 = W_fc[1], bf = b_fc[0];

    const float4 xv = x[idx];

    float h0, h1, c0s, c1s;  // c*s are scaled cell states (c' = S2 * c_true)

    // ---------- t = 0: h=c=0 -> forget gate dead, gates affine in x0 ----------
    {
        const float x0 = xv.x;
        const float pi0 = fmaf(x0, wi[0], bb[0]);
        const float pi1 = fmaf(x0, wi[1], bb[1]);
        const float pg0 = fmaf(x0, wi[4], bb[4]);
        const float pg1 = fmaf(x0, wi[5], bb[5]);
        const float po0 = fmaf(x0, wi[6], bb[6]);
        const float po1 = fmaf(x0, wi[7], bb[7]);
        const float ei0 = fexp2(pi0), ei1 = fexp2(pi1);
        const float eg0 = fexp2(pg0), eg1 = fexp2(pg1);
        const float eo0 = fexp2(po0), eo1 = fexp2(po1);
        const float d0 = 1.f + ei0, d1 = 1.f + ei1;       // i denoms
        const float d2 = eg0 + 1.f, d3 = eg1 + 1.f;       // g denoms
        const float d4 = 1.f + eo0, d5 = 1.f + eo1;       // o denoms
        // scaled g numerators: S2*tanh = (S2*e - S2)/(e+1)
        const float ng0 = fmaf(eg0, S2, -S2);
        const float ng1 = fmaf(eg1, S2, -S2);
        // Montgomery-6
        const float p1 = d0 * d1, p2 = p1 * d2, p3 = p2 * d3, p4 = p3 * d4,
                    p5 = p4 * d5;
        float R = frcp(p5);
        const float v5 = R * p4; R *= d5;
        const float v4 = R * p3; R *= d4;
        const float v3 = R * p2; R *= d3;
        const float v2 = R * p1; R *= d2;
        const float v1 = R * d0;
        const float v0 = R * d1;
        const float gi0 = v0, gi1 = v1;            // sigmoid(i)
        const float gg0 = ng0 * v2, gg1 = ng1 * v3; // S2*tanh(g)
        const float go0 = v4, go1 = v5;            // sigmoid(o)
        c0s = gi0 * gg0;                            // scaled cell state
        c1s = gi1 * gg1;
        // tanh(c) = (2^c' - 1)/(2^c' + 1)
        const float e0 = fexp2(c0s), e1 = fexp2(c1s);
        const float tn0 = e0 - 1.f, tn1 = e1 - 1.f;
        const float td0 = e0 + 1.f, td1 = e1 + 1.f;
        const float Rt = frcp(td0 * td1);
        h0 = go0 * (tn0 * (Rt * td1));
        h1 = go1 * (tn1 * (Rt * td0));
    }

    // ---------- t = 1..3 ----------
    const float xs[3] = {xv.y, xv.z, xv.w};
#pragma unroll
    for (int t = 0; t < 3; ++t) {
        const float xt = xs[t];
        float pre[8];
#pragma unroll
        for (int k = 0; k < 8; ++k)
            pre[k] = fmaf(xt, wi[k], fmaf(h0, wh0[k], fmaf(h1, wh1[k], bb[k])));
        float e[8];
#pragma unroll
        for (int k = 0; k < 8; ++k) e[k] = fexp2(pre[k]);
        // denominators (all positive, bounded)
        const float d0 = 1.f + e[0], d1 = 1.f + e[1];   // i
        const float d2 = 1.f + e[2], d3 = 1.f + e[3];   // f
        const float d4 = e[4] + 1.f, d5 = e[5] + 1.f;   // g
        const float d6 = 1.f + e[6], d7 = 1.f + e[7];   // o
        const float ng0 = fmaf(e[4], S2, -S2);
        const float ng1 = fmaf(e[5], S2, -S2);
        // Montgomery-8: one rcp for 8 inverses
        const float p1 = d0 * d1, p2 = p1 * d2, p3 = p2 * d3, p4 = p3 * d4,
                    p5 = p4 * d5, p6 = p5 * d6, p7 = p6 * d7;
        float R = frcp(p7);
        const float v7 = R * p6; R *= d7;
        const float v6 = R * p5; R *= d6;
        const float v5 = R * p4; R *= d5;
        const float v4 = R * p3; R *= d4;
        const float v3 = R * p2; R *= d3;
        const float v2 = R * p1; R *= d2;
        const float v1 = R * d0;
        const float v0 = R * d1;
        const float gi0 = v0, gi1 = v1;             // sigmoid(i)
        const float gf0 = v2, gf1 = v3;             // sigmoid(f)
        const float gg0 = ng0 * v4, gg1 = ng1 * v5; // S2*tanh(g)
        const float go0 = v6, go1 = v7;             // sigmoid(o)
        c0s = fmaf(gf0, c0s, gi0 * gg0);
        c1s = fmaf(gf1, c1s, gi1 * gg1);
        const float e0 = fexp2(c0s), e1 = fexp2(c1s);
        const float tn0 = e0 - 1.f, tn1 = e1 - 1.f;
        const float td0 = e0 + 1.f, td1 = e1 + 1.f;
        const float Rt = frcp(td0 * td1);
        h0 = go0 * (tn0 * (Rt * td1));
        h1 = go1 * (tn1 * (Rt * td0));
    }

    out[idx] = fmaf(h0, wf0, fmaf(h1, wf1, bf));
}

extern "C" void kernel_launch(void* const* d_in, const int* in_sizes, int n_in,
                              void* d_out, int out_size, void* d_ws, size_t ws_size,
                              hipStream_t stream)
{
    const float4* x    = (const float4*)d_in[0];
    const float*  W_ih = (const float*)d_in[1];
    const float*  W_hh = (const float*)d_in[2];
    const float*  b_ih = (const float*)d_in[3];
    const float*  b_hh = (const float*)d_in[4];
    const float*  W_fc = (const float*)d_in[5];
    const float*  b_fc = (const float*)d_in[6];
    float* out = (float*)d_out;

    const int B = in_sizes[0] / 4;
    const int threads = 256;
    const int blocks = (B + threads - 1) / threads;
    lstm_fused<<<blocks, threads, 0, stream>>>(x, W_ih, W_hh, b_ih, b_hh,
                                               W_fc, b_fc, out, B);
}

// Round 4
// 45.495 us; speedup vs baseline: 1.0697x; 1.0114x over previous
//
#include <hip/hip_runtime.h>

// LSTM_8589935226: B=4194304 independent LSTMs, T=4, I=1, H=2, C=1.
// Round 4:
//  - prep kernel: weight preprocessing (log2e scales folded) once into d_ws
//  - product-inverse trick: Montgomery over {d_i*d_g, d_f, d_o} x2 halves
//  - ILP=2: two independent elements per thread, interleaved by scheduler
//  - scaled cell domain c' = 2*log2e*c so tanh(c) = (2^c'-1)/(2^c'+1)
// Model: cyc = 2V + 16.8T. Per elem V~245,T~46 -> ~1263 cyc -> predict ~36us.

__device__ __forceinline__ float fexp2(float x) { return __builtin_amdgcn_exp2f(x); }
__device__ __forceinline__ float frcp(float x)  { return __builtin_amdgcn_rcpf(x); }

#define S2C 2.8853900817779268f   // 2*log2(e)

// ws layout: [0..7]=wi, [8..15]=wh0, [16..23]=wh1, [24..31]=bb, [32]=wf0,
// [33]=wf1, [34]=bf
__global__ void lstm_prep(const float* __restrict__ W_ih,
                          const float* __restrict__ W_hh,
                          const float* __restrict__ b_ih,
                          const float* __restrict__ b_hh,
                          const float* __restrict__ W_fc,
                          const float* __restrict__ b_fc,
                          float* __restrict__ ws)
{
    const int k = threadIdx.x;
    if (k < 8) {
        const float L2E = 1.4426950408889634f;
        // gate order i(0,1) f(2,3) g(4,5) o(6,7); sigmoid rows * -log2e,
        // tanh(g) rows * +2*log2e
        const float s = (k == 4 || k == 5) ? S2C : -L2E;
        ws[k]      = W_ih[k] * s;
        ws[8 + k]  = W_hh[2 * k] * s;
        ws[16 + k] = W_hh[2 * k + 1] * s;
        ws[24 + k] = (b_ih[k] + b_hh[k]) * s;
    } else if (k == 8) {
        ws[32] = W_fc[0];
        ws[33] = W_fc[1];
        ws[34] = b_fc[0];
    }
}

__device__ __forceinline__ float lstm_elem(const float4 xv,
                                           const float* __restrict__ wi,
                                           const float* __restrict__ wh0,
                                           const float* __restrict__ wh1,
                                           const float* __restrict__ bb,
                                           float wf0, float wf1, float bf)
{
    float h0, h1, c0, c1;  // c in scaled domain (c' = S2C * c_true)

    // ---- t = 0: h=c=0 -> f-gate dead, gates affine in x0 ----
    {
        const float x0 = xv.x;
        const float pi0 = fmaf(x0, wi[0], bb[0]);
        const float pi1 = fmaf(x0, wi[1], bb[1]);
        const float pg0 = fmaf(x0, wi[4], bb[4]);
        const float pg1 = fmaf(x0, wi[5], bb[5]);
        const float po0 = fmaf(x0, wi[6], bb[6]);
        const float po1 = fmaf(x0, wi[7], bb[7]);
        const float ei0 = fexp2(pi0), ei1 = fexp2(pi1);
        const float eg0 = fexp2(pg0), eg1 = fexp2(pg1);
        const float eo0 = fexp2(po0), eo1 = fexp2(po1);
        const float di0 = 1.f + ei0, di1 = 1.f + ei1;
        const float dg0 = 1.f + eg0, dg1 = 1.f + eg1;
        const float do0 = 1.f + eo0, do1 = 1.f + eo1;
        const float m0 = di0 * dg0, m1 = di1 * dg1;
        // Montgomery-4 over {m0, do0, m1, do1}
        const float P1 = m0 * do0, P2 = P1 * m1, P3 = P2 * do1;
        float R = frcp(P3);
        const float vDo1 = R * P2;  R *= do1;
        const float vM1  = R * P1;  R *= m1;
        const float vDo0 = R * m0;  R *= do0;
        const float vM0  = R;
        const float ng0 = fmaf(eg0, S2C, -S2C);
        const float ng1 = fmaf(eg1, S2C, -S2C);
        c0 = ng0 * vM0;           // sigmoid(i)*S2*tanh(g), scaled cell
        c1 = ng1 * vM1;
        const float ec0 = fexp2(c0), ec1 = fexp2(c1);
        const float tn0 = ec0 - 1.f, tn1 = ec1 - 1.f;
        const float td0 = ec0 + 1.f, td1 = ec1 + 1.f;
        const float Rt = frcp(td0 * td1);
        h0 = vDo0 * (tn0 * (Rt * td1));
        h1 = vDo1 * (tn1 * (Rt * td0));
    }

    // ---- t = 1..3 ----
    const float xs[3] = {xv.y, xv.z, xv.w};
#pragma unroll
    for (int t = 0; t < 3; ++t) {
        const float xt = xs[t];
        float pr[8];
#pragma unroll
        for (int k = 0; k < 8; ++k)
            pr[k] = fmaf(xt, wi[k], fmaf(h0, wh0[k], fmaf(h1, wh1[k], bb[k])));
        const float e0 = fexp2(pr[0]), e1 = fexp2(pr[1]);
        const float e2 = fexp2(pr[2]), e3 = fexp2(pr[3]);
        const float e4 = fexp2(pr[4]), e5 = fexp2(pr[5]);
        const float e6 = fexp2(pr[6]), e7 = fexp2(pr[7]);
        const float di0 = 1.f + e0, di1 = 1.f + e1;
        const float df0 = 1.f + e2, df1 = 1.f + e3;
        const float dg0 = 1.f + e4, dg1 = 1.f + e5;
        const float do0 = 1.f + e6, do1 = 1.f + e7;
        const float m0 = di0 * dg0, m1 = di1 * dg1;
        // Montgomery-6 over {m0, df0, do0, m1, df1, do1}
        const float P1 = m0 * df0, P2 = P1 * do0, P3 = P2 * m1,
                    P4 = P3 * df1, P5 = P4 * do1;
        float R = frcp(P5);
        const float vDo1 = R * P4;  R *= do1;
        const float vDf1 = R * P3;  R *= df1;
        const float vM1  = R * P2;  R *= m1;
        const float vDo0 = R * P1;  R *= do0;
        const float vDf0 = R * m0;  R *= df0;
        const float vM0  = R;
        const float ng0 = fmaf(e4, S2C, -S2C);
        const float ng1 = fmaf(e5, S2C, -S2C);
        c0 = fmaf(vDf0, c0, ng0 * vM0);
        c1 = fmaf(vDf1, c1, ng1 * vM1);
        const float ec0 = fexp2(c0), ec1 = fexp2(c1);
        const float tn0 = ec0 - 1.f, tn1 = ec1 - 1.f;
        const float td0 = ec0 + 1.f, td1 = ec1 + 1.f;
        const float Rt = frcp(td0 * td1);
        h0 = vDo0 * (tn0 * (Rt * td1));
        h1 = vDo1 * (tn1 * (Rt * td0));
    }

    return fmaf(h0, wf0, fmaf(h1, wf1, bf));
}

__global__ __launch_bounds__(256) void lstm_main(
    const float4* __restrict__ x,   // [B] float4 per element
    const float*  __restrict__ ws,  // preprocessed constants
    float2* __restrict__ out,       // [B/2]
    int B2)                         // B/2
{
    const int idx = blockIdx.x * blockDim.x + threadIdx.x;
    if (idx >= B2) return;

    const float* wi  = ws;
    const float* wh0 = ws + 8;
    const float* wh1 = ws + 16;
    const float* bb  = ws + 24;
    const float wf0 = ws[32], wf1 = ws[33], bf = ws[34];

    const float4 xa = x[2 * idx];
    const float4 xb = x[2 * idx + 1];

    // Two independent chains; single basic block -> scheduler interleaves.
    const float oa = lstm_elem(xa, wi, wh0, wh1, bb, wf0, wf1, bf);
    const float ob = lstm_elem(xb, wi, wh0, wh1, bb, wf0, wf1, bf);

    float2 o; o.x = oa; o.y = ob;
    out[idx] = o;
}

extern "C" void kernel_launch(void* const* d_in, const int* in_sizes, int n_in,
                              void* d_out, int out_size, void* d_ws, size_t ws_size,
                              hipStream_t stream)
{
    const float*  W_ih = (const float*)d_in[1];
    const float*  W_hh = (const float*)d_in[2];
    const float*  b_ih = (const float*)d_in[3];
    const float*  b_hh = (const float*)d_in[4];
    const float*  W_fc = (const float*)d_in[5];
    const float*  b_fc = (const float*)d_in[6];
    float* ws = (float*)d_ws;

    lstm_prep<<<1, 64, 0, stream>>>(W_ih, W_hh, b_ih, b_hh, W_fc, b_fc, ws);

    const float4* x = (const float4*)d_in[0];
    float2* out = (float2*)d_out;
    const int B = in_sizes[0] / 4;
    const int B2 = B / 2;
    const int threads = 256;
    const int blocks = (B2 + threads - 1) / threads;
    lstm_main<<<blocks, threads, 0, stream>>>(x, ws, out, B2);
}